// Round 3
// baseline (317.699 us; speedup 1.0000x reference)
//
#include <hip/hip_runtime.h>
#include <stdint.h>

#define NROWS 16384
#define D 4096

typedef __bf16 bf16x8 __attribute__((ext_vector_type(8)));
typedef float  f32x4  __attribute__((ext_vector_type(4)));

__device__ inline unsigned short f2bf(float f) {
    unsigned u = __float_as_uint(f);
    u += 0x7fffu + ((u >> 16) & 1u);
    return (unsigned short)(u >> 16);
}

// ---------------- setup: inverse permutation ----------------
__global__ __launch_bounds__(256) void k_inv_perm(const int* __restrict__ perm,
                                                  int* __restrict__ inv) {
    int d = blockIdx.x * blockDim.x + threadIdx.x;
    if (d < D) inv[perm[d]] = d;
}

// ---------------- Wco build: c1[X][y][z][pqr] = sum_x fo0[X,x] core[x,y,z,pqr]
__global__ __launch_bounds__(256) void k_b1(const float* __restrict__ core,
                                            const float* __restrict__ fo0,
                                            float* __restrict__ c1) {
    int g = blockIdx.x * 256 + threadIdx.x;      // 524288
    int pqr = g & 511, z = (g >> 9) & 7, y = (g >> 12) & 7, X = g >> 15;
    float s = 0.f;
    #pragma unroll
    for (int x = 0; x < 8; ++x)
        s += fo0[X * 8 + x] * core[x * 32768 + y * 4096 + z * 512 + pqr];
    c1[g] = s;
}

// c2[X][Y][z][pqr] = sum_y fo1[Y,y] c1[X,y,z,pqr]
__global__ __launch_bounds__(256) void k_b2(const float* __restrict__ c1,
                                            const float* __restrict__ fo1,
                                            float* __restrict__ c2) {
    int g = blockIdx.x * 256 + threadIdx.x;      // 1048576
    int pqr = g & 511, z = (g >> 9) & 7, Y = (g >> 12) & 15, X = g >> 16;
    float s = 0.f;
    #pragma unroll
    for (int y = 0; y < 8; ++y)
        s += fo1[Y * 8 + y] * c1[X * 32768 + y * 4096 + z * 512 + pqr];
    c2[g] = s;
}

// Wco_bf[n=XYZ][k=pqr] = sum_z fo2[Z,z] c2[X,Y,z,pqr]  (packed 2 bf16 / u32)
__global__ __launch_bounds__(256) void k_b3(const float* __restrict__ c2,
                                            const float* __restrict__ fo2,
                                            unsigned int* __restrict__ wco) {
    int g = blockIdx.x * 256 + threadIdx.x;      // 1048576
    int kp = g & 255, n = g >> 8;
    int X = n >> 8, Y = (n >> 4) & 15, Z = n & 15;
    float s0 = 0.f, s1 = 0.f;
    #pragma unroll
    for (int z = 0; z < 8; ++z) {
        float2 v = *(const float2*)&c2[X * 65536 + Y * 4096 + z * 512 + 2 * kp];
        float f = fo2[Z * 8 + z];
        s0 += f * v.x; s1 += f * v.y;
    }
    wco[g] = (unsigned)f2bf(s0) | ((unsigned)f2bf(s1) << 16);
}

// ---------------- input contraction: one row per block -> t3 bf16 ----------------
__global__ __launch_bounds__(256, 4) void k_t3(const float* __restrict__ x,
                                               const float* __restrict__ fi0,
                                               const float* __restrict__ fi1,
                                               const float* __restrict__ fi2,
                                               const int* __restrict__ inv,
                                               unsigned int* __restrict__ t3out) {
    __shared__ float xr[4096];    // 16 KB
    __shared__ float t1[2048];    //  8 KB
    __shared__ float t2[1024];    //  4 KB
    __shared__ float t3l[512];    //  2 KB

    const int tid = threadIdx.x;
    const int n = blockIdx.x;

    // coalesced row load + permuted scatter into LDS
    const float4* xrow = (const float4*)(x + (size_t)n * D);
    #pragma unroll
    for (int it = 0; it < 4; ++it) {
        float4 v = xrow[tid + it * 256];
        int4  iv = ((const int4*)inv)[tid + it * 256];
        xr[iv.x] = v.x; xr[iv.y] = v.y; xr[iv.z] = v.z; xr[iv.w] = v.w;
    }
    __syncthreads();

    // step 3: t1[p][bc] = sum_a xr[a*256+bc] * fi0[a,p]
    {
        float a8[8] = {0,0,0,0,0,0,0,0};
        #pragma unroll
        for (int a = 0; a < 16; ++a) {
            float v = xr[a * 256 + tid];
            #pragma unroll
            for (int p = 0; p < 8; ++p) a8[p] += v * fi0[a * 8 + p];
        }
        #pragma unroll
        for (int p = 0; p < 8; ++p) t1[p * 256 + tid] = a8[p];
    }
    __syncthreads();

    // step 4: t2[p][q][c] = sum_b t1[p][b*16+c] * fi1[b,q]   (thread: p,c,q-half)
    {
        const int p = tid >> 5, c = (tid >> 1) & 15, qh = tid & 1;
        float a4[4] = {0,0,0,0};
        #pragma unroll
        for (int b = 0; b < 16; ++b) {
            float v = t1[p * 256 + b * 16 + c];
            #pragma unroll
            for (int qi = 0; qi < 4; ++qi) a4[qi] += v * fi1[b * 8 + qh * 4 + qi];
        }
        #pragma unroll
        for (int qi = 0; qi < 4; ++qi) t2[p * 128 + (qh * 4 + qi) * 16 + c] = a4[qi];
    }
    __syncthreads();

    // step 5: t3[p][q][rr] = sum_c t2[p][q][c] * fi2[c,rr]   (thread: p,q,rr-quarter)
    {
        const int p = tid >> 5, q = (tid >> 2) & 7, rh = tid & 3;
        float a2[2] = {0,0};
        #pragma unroll
        for (int c = 0; c < 16; ++c) {
            float v = t2[p * 128 + q * 16 + c];
            #pragma unroll
            for (int ri = 0; ri < 2; ++ri) a2[ri] += v * fi2[c * 8 + rh * 2 + ri];
        }
        t3l[p * 64 + q * 8 + rh * 2 + 0] = a2[0];
        t3l[p * 64 + q * 8 + rh * 2 + 1] = a2[1];
    }
    __syncthreads();

    // pack to bf16 and store (coalesced u32)
    t3out[(size_t)n * 256 + tid] =
        (unsigned)f2bf(t3l[2 * tid]) | ((unsigned)f2bf(t3l[2 * tid + 1]) << 16);
}

// ---------------- GEMM: out[n][4096] = t3[n][512] @ Wco^T + epilogue ----------------
// 128x128 tile, BK=64, 4 waves (2x2 of 64x64), mfma_f32_16x16x32_bf16
__global__ __launch_bounds__(256) void k_gemm(const __bf16* __restrict__ t3,
                                              const __bf16* __restrict__ wco,
                                              const float* __restrict__ pds,
                                              const float* __restrict__ alphap,
                                              const float* __restrict__ bias,
                                              float* __restrict__ out) {
    __shared__ __bf16 lA[8192];   // [k4 0..7][row 0..127][8]  16 KB
    __shared__ __bf16 lB[8192];   // same for B               16 KB

    const int tid = threadIdx.x, lane = tid & 63, wv = tid >> 6;

    // XCD-chunked bijective swizzle (4096 blocks / 8 XCDs = 512 each),
    // n FASTEST within a chunk so the A-panel (128 KB) stays L2-hot
    // across its 32 consecutive consumers; each XCD owns 16 contiguous
    // m-panels (A chunk 2 MB) and sweeps B (4 MB) -> both ~L2-resident.
    const int bid = blockIdx.x;
    const int wgid = (bid & 7) * 512 + (bid >> 3);
    const int m0 = (wgid >> 5) * 128;      // m-panel: 16 contiguous per XCD
    const int n0 = (wgid & 31) * 128;      // n fastest
    const int wm = wv >> 1, wn = wv & 1;
    const int l15 = lane & 15, l4 = lane >> 4;

    // preload epilogue data (hidden under the K-loop)
    const float alpha = alphap[0];
    float pv[4], bv[4];
    #pragma unroll
    for (int nt = 0; nt < 4; ++nt) {
        const int col = n0 + wn * 64 + nt * 16 + l15;
        pv[nt] = pds[col] * alpha;
        bv[nt] = bias[col];
    }

    f32x4 acc[4][4] = {};

    for (int ks = 0; ks < 8; ++ks) {
        #pragma unroll
        for (int i = 0; i < 4; ++i) {
            const int u = i * 256 + wv * 64 + lane;
            const int r = u & 127, k4 = u >> 7;
            const __bf16* ga = t3 + (size_t)(m0 + r) * 512 + ks * 64 + k4 * 8;
            __builtin_amdgcn_global_load_lds(
                (const __attribute__((address_space(1))) void*)ga,
                (__attribute__((address_space(3))) void*)(lA + i * 2048 + wv * 512),
                16, 0, 0);
            const __bf16* gb = wco + (size_t)(n0 + r) * 512 + ks * 64 + k4 * 8;
            __builtin_amdgcn_global_load_lds(
                (const __attribute__((address_space(1))) void*)gb,
                (__attribute__((address_space(3))) void*)(lB + i * 2048 + wv * 512),
                16, 0, 0);
        }
        __syncthreads();
        #pragma unroll
        for (int kk = 0; kk < 2; ++kk) {
            const int k4f = kk * 4 + l4;
            bf16x8 af[4], bfr[4];
            #pragma unroll
            for (int mt = 0; mt < 4; ++mt)
                af[mt] = *(const bf16x8*)&lA[(k4f * 128 + wm * 64 + mt * 16 + l15) * 8];
            #pragma unroll
            for (int nt = 0; nt < 4; ++nt)
                bfr[nt] = *(const bf16x8*)&lB[(k4f * 128 + wn * 64 + nt * 16 + l15) * 8];
            #pragma unroll
            for (int mt = 0; mt < 4; ++mt)
                #pragma unroll
                for (int nt = 0; nt < 4; ++nt)
                    acc[mt][nt] = __builtin_amdgcn_mfma_f32_16x16x32_bf16(
                        af[mt], bfr[nt], acc[mt][nt], 0, 0, 0);
        }
        __syncthreads();
    }

    // epilogue: scale * alpha + bias
    #pragma unroll
    for (int nt = 0; nt < 4; ++nt) {
        const int col = n0 + wn * 64 + nt * 16 + l15;
        #pragma unroll
        for (int mt = 0; mt < 4; ++mt) {
            const int row = m0 + wm * 64 + mt * 16 + l4 * 4;
            #pragma unroll
            for (int j = 0; j < 4; ++j)
                out[(size_t)(row + j) * 4096 + col] = acc[mt][nt][j] * pv[nt] + bv[nt];
        }
    }
}

extern "C" void kernel_launch(void* const* d_in, const int* in_sizes, int n_in,
                              void* d_out, int out_size, void* d_ws, size_t ws_size,
                              hipStream_t stream) {
    const float* x     = (const float*)d_in[0];
    const float* core  = (const float*)d_in[1];
    const float* fi0   = (const float*)d_in[2];
    const float* fi1   = (const float*)d_in[3];
    const float* fi2   = (const float*)d_in[4];
    const float* fo0   = (const float*)d_in[5];
    const float* fo1   = (const float*)d_in[6];
    const float* fo2   = (const float*)d_in[7];
    const float* pds   = (const float*)d_in[8];
    const float* alpha = (const float*)d_in[9];
    const float* bias  = (const float*)d_in[10];
    const int*   perm  = (const int*)d_in[11];
    float* outp = (float*)d_out;

    char* ws = (char*)d_ws;
    int*          inv  = (int*)(ws);                         // 16 KB
    float*        c1   = (float*)(ws + 16384);               // 2 MB
    float*        c2   = (float*)(ws + 16384 + 2097152);     // 4 MB
    unsigned int* wco  = (unsigned int*)(ws + 16384 + 2097152 + 4194304);   // 4 MB
    unsigned int* t3ws = (unsigned int*)(ws + 16384 + 2097152 + 8388608);   // 16 MB

    k_inv_perm<<<16, 256, 0, stream>>>(perm, inv);
    k_b1<<<2048, 256, 0, stream>>>(core, fo0, c1);
    k_b2<<<4096, 256, 0, stream>>>(c1, fo1, c2);
    k_b3<<<4096, 256, 0, stream>>>(c2, fo2, wco);
    k_t3<<<NROWS, 256, 0, stream>>>(x, fi0, fi1, fi2, inv, t3ws);
    k_gemm<<<4096, 256, 0, stream>>>((const __bf16*)t3ws, (const __bf16*)wco,
                                     pds, alpha, bias, outp);
}

// Round 4
// 253.739 us; speedup vs baseline: 1.2521x; 1.2521x over previous
//
#include <hip/hip_runtime.h>
#include <stdint.h>

#define NROWS 16384
#define D 4096

typedef __bf16 bf16x8 __attribute__((ext_vector_type(8)));
typedef float  f32x4  __attribute__((ext_vector_type(4)));

__device__ inline unsigned short f2bf(float f) {
    unsigned u = __float_as_uint(f);
    u += 0x7fffu + ((u >> 16) & 1u);
    return (unsigned short)(u >> 16);
}

// ---------------- setup: inverse permutation ----------------
__global__ __launch_bounds__(256) void k_inv_perm(const int* __restrict__ perm,
                                                  int* __restrict__ inv) {
    int d = blockIdx.x * blockDim.x + threadIdx.x;
    if (d < D) inv[perm[d]] = d;
}

// ---------------- Wco build: c1[X][y][z][pqr] = sum_x fo0[X,x] core[x,y,z,pqr]
__global__ __launch_bounds__(256) void k_b1(const float* __restrict__ core,
                                            const float* __restrict__ fo0,
                                            float* __restrict__ c1) {
    int g = blockIdx.x * 256 + threadIdx.x;      // 524288
    int pqr = g & 511, z = (g >> 9) & 7, y = (g >> 12) & 7, X = g >> 15;
    float s = 0.f;
    #pragma unroll
    for (int x = 0; x < 8; ++x)
        s += fo0[X * 8 + x] * core[x * 32768 + y * 4096 + z * 512 + pqr];
    c1[g] = s;
}

// c2[X][Y][z][pqr] = sum_y fo1[Y,y] c1[X,y,z,pqr]
__global__ __launch_bounds__(256) void k_b2(const float* __restrict__ c1,
                                            const float* __restrict__ fo1,
                                            float* __restrict__ c2) {
    int g = blockIdx.x * 256 + threadIdx.x;      // 1048576
    int pqr = g & 511, z = (g >> 9) & 7, Y = (g >> 12) & 15, X = g >> 16;
    float s = 0.f;
    #pragma unroll
    for (int y = 0; y < 8; ++y)
        s += fo1[Y * 8 + y] * c1[X * 32768 + y * 4096 + z * 512 + pqr];
    c2[g] = s;
}

// Wco in GEMM staging layout [ks][k4][n][8bf16] (u32-pair granularity):
// element k of row n lives at ((ks*8+k4)*4096 + n)*8 + (k&7), ks=k>>6, k4=(k>>3)&7
__global__ __launch_bounds__(256) void k_b3(const float* __restrict__ c2,
                                            const float* __restrict__ fo2,
                                            unsigned int* __restrict__ wco) {
    int g = blockIdx.x * 256 + threadIdx.x;      // 1048576
    int kp = g & 255, n = g >> 8;                // kp = bf16-pair index, k=2*kp
    int X = n >> 8, Y = (n >> 4) & 15, Z = n & 15;
    float s0 = 0.f, s1 = 0.f;
    #pragma unroll
    for (int z = 0; z < 8; ++z) {
        float2 v = *(const float2*)&c2[X * 65536 + Y * 4096 + z * 512 + 2 * kp];
        float f = fo2[Z * 8 + z];
        s0 += f * v.x; s1 += f * v.y;
    }
    const int ks = kp >> 5, k4 = (kp >> 2) & 7, w = kp & 3;
    wco[(((size_t)ks * 8 + k4) * 4096 + n) * 4 + w] =
        (unsigned)f2bf(s0) | ((unsigned)f2bf(s1) << 16);
}

// ---------------- input contraction: one row per block -> t3 bf16 ----------------
// t3 stored in GEMM staging layout [ks][k4][n][8bf16]
__global__ __launch_bounds__(256, 4) void k_t3(const float* __restrict__ x,
                                               const float* __restrict__ fi0,
                                               const float* __restrict__ fi1,
                                               const float* __restrict__ fi2,
                                               const int* __restrict__ inv,
                                               unsigned int* __restrict__ t3out) {
    __shared__ float xr[4096];    // 16 KB
    __shared__ float t1[2048];    //  8 KB
    __shared__ float t2[1024];    //  4 KB
    __shared__ float t3l[512];    //  2 KB

    const int tid = threadIdx.x;
    const int n = blockIdx.x;

    // coalesced row load + permuted scatter into LDS
    const float4* xrow = (const float4*)(x + (size_t)n * D);
    #pragma unroll
    for (int it = 0; it < 4; ++it) {
        float4 v = xrow[tid + it * 256];
        int4  iv = ((const int4*)inv)[tid + it * 256];
        xr[iv.x] = v.x; xr[iv.y] = v.y; xr[iv.z] = v.z; xr[iv.w] = v.w;
    }
    __syncthreads();

    // step 3: t1[p][bc] = sum_a xr[a*256+bc] * fi0[a,p]
    {
        float a8[8] = {0,0,0,0,0,0,0,0};
        #pragma unroll
        for (int a = 0; a < 16; ++a) {
            float v = xr[a * 256 + tid];
            #pragma unroll
            for (int p = 0; p < 8; ++p) a8[p] += v * fi0[a * 8 + p];
        }
        #pragma unroll
        for (int p = 0; p < 8; ++p) t1[p * 256 + tid] = a8[p];
    }
    __syncthreads();

    // step 4: t2[p][q][c] = sum_b t1[p][b*16+c] * fi1[b,q]   (thread: p,c,q-half)
    {
        const int p = tid >> 5, c = (tid >> 1) & 15, qh = tid & 1;
        float a4[4] = {0,0,0,0};
        #pragma unroll
        for (int b = 0; b < 16; ++b) {
            float v = t1[p * 256 + b * 16 + c];
            #pragma unroll
            for (int qi = 0; qi < 4; ++qi) a4[qi] += v * fi1[b * 8 + qh * 4 + qi];
        }
        #pragma unroll
        for (int qi = 0; qi < 4; ++qi) t2[p * 128 + (qh * 4 + qi) * 16 + c] = a4[qi];
    }
    __syncthreads();

    // step 5: t3[p][q][rr] = sum_c t2[p][q][c] * fi2[c,rr]   (thread: p,q,rr-quarter)
    {
        const int p = tid >> 5, q = (tid >> 2) & 7, rh = tid & 3;
        float a2[2] = {0,0};
        #pragma unroll
        for (int c = 0; c < 16; ++c) {
            float v = t2[p * 128 + q * 16 + c];
            #pragma unroll
            for (int ri = 0; ri < 2; ++ri) a2[ri] += v * fi2[c * 8 + rh * 2 + ri];
        }
        t3l[p * 64 + q * 8 + rh * 2 + 0] = a2[0];
        t3l[p * 64 + q * 8 + rh * 2 + 1] = a2[1];
    }
    __syncthreads();

    // pack to bf16, store in [ks][k4][n][8] layout (pair index = tid, k = 2*tid)
    {
        const int ks = tid >> 5, k4 = (tid >> 2) & 7, w = tid & 3;
        t3out[(((size_t)ks * 8 + k4) * NROWS + n) * 4 + w] =
            (unsigned)f2bf(t3l[2 * tid]) | ((unsigned)f2bf(t3l[2 * tid + 1]) << 16);
    }
}

// ---------------- GEMM: out[n][4096] = t3 @ Wco^T + epilogue ----------------
// 128x128 tile, BK=64, 4 waves (2x2 of 64x64), mfma_f32_16x16x32_bf16.
// Inputs pre-tiled as [ks][k4][row][8] so staging is fully coalesced and the
// LDS image is the proven zero-conflict [k4][row][8] layout.
__global__ __launch_bounds__(256, 2) void k_gemm(const __bf16* __restrict__ t3,
                                                 const __bf16* __restrict__ wco,
                                                 const float* __restrict__ pds,
                                                 const float* __restrict__ alphap,
                                                 const float* __restrict__ bias,
                                                 float* __restrict__ out) {
    __shared__ __bf16 lA[8192];   // [k4 0..7][row 0..127][8]  16 KB
    __shared__ __bf16 lB[8192];   // same for B               16 KB

    const int tid = threadIdx.x, lane = tid & 63, wv = tid >> 6;

    // XCD-chunked bijective swizzle, n fastest (A-panel L2-hot per XCD)
    const int bid = blockIdx.x;
    const int wgid = (bid & 7) * 512 + (bid >> 3);
    const int m0 = (wgid >> 5) * 128;      // 16 contiguous m-panels per XCD
    const int n0 = (wgid & 31) * 128;      // n fastest
    const int wm = wv >> 1, wn = wv & 1;
    const int l15 = lane & 15, l4 = lane >> 4;

    // preload epilogue data (hidden under the K-loop)
    const float alpha = alphap[0];
    float pv[4], bv[4];
    #pragma unroll
    for (int nt = 0; nt < 4; ++nt) {
        const int col = n0 + wn * 64 + nt * 16 + l15;
        pv[nt] = pds[col] * alpha;
        bv[nt] = bias[col];
    }

    f32x4 acc[4][4] = {};

    for (int ks = 0; ks < 8; ++ks) {
        #pragma unroll
        for (int i = 0; i < 4; ++i) {
            const int c = i * 256 + tid;            // 16B chunk id, 0..1023
            const int k4 = c >> 7, r = c & 127;     // k4 wave-uniform, r=lane-contig
            const __bf16* ga = t3 + ((size_t)(ks * 8 + k4) * NROWS + m0 + r) * 8;
            __builtin_amdgcn_global_load_lds(
                (const __attribute__((address_space(1))) void*)ga,
                (__attribute__((address_space(3))) void*)(lA + (size_t)c * 8),
                16, 0, 0);
            const __bf16* gb = wco + ((size_t)(ks * 8 + k4) * 4096 + n0 + r) * 8;
            __builtin_amdgcn_global_load_lds(
                (const __attribute__((address_space(1))) void*)gb,
                (__attribute__((address_space(3))) void*)(lB + (size_t)c * 8),
                16, 0, 0);
        }
        __syncthreads();
        #pragma unroll
        for (int kk = 0; kk < 2; ++kk) {
            const int k4f = kk * 4 + l4;
            bf16x8 af[4], bfr[4];
            #pragma unroll
            for (int mt = 0; mt < 4; ++mt)
                af[mt] = *(const bf16x8*)&lA[(k4f * 128 + wm * 64 + mt * 16 + l15) * 8];
            #pragma unroll
            for (int nt = 0; nt < 4; ++nt)
                bfr[nt] = *(const bf16x8*)&lB[(k4f * 128 + wn * 64 + nt * 16 + l15) * 8];
            #pragma unroll
            for (int mt = 0; mt < 4; ++mt)
                #pragma unroll
                for (int nt = 0; nt < 4; ++nt)
                    acc[mt][nt] = __builtin_amdgcn_mfma_f32_16x16x32_bf16(
                        af[mt], bfr[nt], acc[mt][nt], 0, 0, 0);
        }
        __syncthreads();
    }

    // epilogue: scale * alpha + bias
    #pragma unroll
    for (int nt = 0; nt < 4; ++nt) {
        const int col = n0 + wn * 64 + nt * 16 + l15;
        #pragma unroll
        for (int mt = 0; mt < 4; ++mt) {
            const int row = m0 + wm * 64 + mt * 16 + l4 * 4;
            #pragma unroll
            for (int j = 0; j < 4; ++j)
                out[(size_t)(row + j) * 4096 + col] = acc[mt][nt][j] * pv[nt] + bv[nt];
        }
    }
}

extern "C" void kernel_launch(void* const* d_in, const int* in_sizes, int n_in,
                              void* d_out, int out_size, void* d_ws, size_t ws_size,
                              hipStream_t stream) {
    const float* x     = (const float*)d_in[0];
    const float* core  = (const float*)d_in[1];
    const float* fi0   = (const float*)d_in[2];
    const float* fi1   = (const float*)d_in[3];
    const float* fi2   = (const float*)d_in[4];
    const float* fo0   = (const float*)d_in[5];
    const float* fo1   = (const float*)d_in[6];
    const float* fo2   = (const float*)d_in[7];
    const float* pds   = (const float*)d_in[8];
    const float* alpha = (const float*)d_in[9];
    const float* bias  = (const float*)d_in[10];
    const int*   perm  = (const int*)d_in[11];
    float* outp = (float*)d_out;

    char* ws = (char*)d_ws;
    int*          inv  = (int*)(ws);                         // 16 KB
    float*        c1   = (float*)(ws + 16384);               // 2 MB
    float*        c2   = (float*)(ws + 16384 + 2097152);     // 4 MB
    unsigned int* wco  = (unsigned int*)(ws + 16384 + 2097152 + 4194304);   // 4 MB
    unsigned int* t3ws = (unsigned int*)(ws + 16384 + 2097152 + 8388608);   // 16 MB

    k_inv_perm<<<16, 256, 0, stream>>>(perm, inv);
    k_b1<<<2048, 256, 0, stream>>>(core, fo0, c1);
    k_b2<<<4096, 256, 0, stream>>>(c1, fo1, c2);
    k_b3<<<4096, 256, 0, stream>>>(c2, fo2, wco);
    k_t3<<<NROWS, 256, 0, stream>>>(x, fi0, fi1, fi2, inv, t3ws);
    k_gemm<<<4096, 256, 0, stream>>>((const __bf16*)t3ws, (const __bf16*)wco,
                                     pds, alpha, bias, outp);
}